// Round 17
// baseline (269.634 us; speedup 1.0000x reference)
//
#include <hip/hip_runtime.h>

#define D 128
#define CAP 96   // slot capacity per node; deg ~ Poisson(32), P(>96) ~ 1e-18

typedef __attribute__((ext_vector_type(8))) short bf16x8;
typedef __attribute__((ext_vector_type(4))) float f32x4;

// ---------------- bf16 helpers (RTN-even) ----------------
__device__ __forceinline__ unsigned short f2bf(float f) {
  union { float f; unsigned int u; } c; c.f = f;
  unsigned int u = c.u;
  unsigned int r = (u + 0x7fffu + ((u >> 16) & 1u)) >> 16;
  return (unsigned short)r;
}
__device__ __forceinline__ float bf2f(unsigned short h) {
  return __uint_as_float(((unsigned int)h) << 16);
}
__device__ __forceinline__ float bf_lo(unsigned int w) {
  return __uint_as_float(w << 16);
}
__device__ __forceinline__ float bf_hi(unsigned int w) {
  return __uint_as_float(w & 0xffff0000u);
}
__device__ __forceinline__ void split2(float a, float b, unsigned int& hi, unsigned int& lo) {
  unsigned short ha = f2bf(a), hb = f2bf(b);
  unsigned short la = f2bf(a - bf2f(ha)), lb = f2bf(b - bf2f(hb));
  hi = (unsigned int)ha | ((unsigned int)hb << 16);
  lo = (unsigned int)la | ((unsigned int)lb << 16);
}

// A-fragment layout: Af[((t*12 + s)*64 + (row&15) + 16*((k&31)>>3))*8 + (k&7)]
__device__ __forceinline__ void frag_write(unsigned short* __restrict__ Afh,
                                           unsigned short* __restrict__ Afl,
                                           int t, int r, int k, float a, float b) {
  unsigned int hh, hl;
  split2(a, b, hh, hl);
  int s = k >> 5, ksub = (k & 31) >> 3, e = k & 7;
  size_t addr = ((size_t)(t * 12 + s) * 64 + r + 16 * ksub) * 8 + e;
  *(unsigned int*)&Afh[addr] = hh;
  *(unsigned int*)&Afl[addr] = hl;
}

// ---------------- GEMM tile worker ----------------
__device__ void gemm_tile(
    const unsigned short* __restrict__ Afh, const unsigned short* __restrict__ Afl,
    int ksteps,
    const unsigned short* __restrict__ Bfh, const unsigned short* __restrict__ Bfl,
    int outcol0, float* __restrict__ C, int ldc,
    unsigned short* __restrict__ Hb, int N, int ntiles, int log2ny, int wgid) {
  const int w = threadIdx.x >> 6, l = threadIdx.x & 63;
  const int wr = w & 1, wc = w >> 1;
  const int rowblk = wgid >> log2ny;
  const int panel = wgid - (rowblk << log2ny);
  const int rowbase = rowblk * 64 + wr * 32;
  const int ntg0 = panel * 4 + wc * 2;

  int t_[2];
#pragma unroll
  for (int tr = 0; tr < 2; ++tr) {
    int t = (rowbase >> 4) + tr;
    t_[tr] = (t < ntiles) ? t : (ntiles - 1);
  }

  const size_t loff = (size_t)l * 8;
  const unsigned short* ah[2];
  const unsigned short* al[2];
#pragma unroll
  for (int tr = 0; tr < 2; ++tr) {
    ah[tr] = Afh + (size_t)t_[tr] * 12 * 512 + loff;
    al[tr] = Afl + (size_t)t_[tr] * 12 * 512 + loff;
  }
  const unsigned short* bh[2];
  const unsigned short* bl[2];
#pragma unroll
  for (int nt = 0; nt < 2; ++nt) {
    bh[nt] = Bfh + (size_t)(ntg0 + nt) * ksteps * 512 + loff;
    bl[nt] = Bfl + (size_t)(ntg0 + nt) * ksteps * 512 + loff;
  }

  f32x4 acc[2][2] = {};
  for (int s = 0; s < ksteps; ++s) {
    bf16x8 Ah[2], Al[2], Bh[2], Bl[2];
#pragma unroll
    for (int tr = 0; tr < 2; ++tr) {
      Ah[tr] = *(const bf16x8*)(ah[tr] + (size_t)s * 512);
      Al[tr] = *(const bf16x8*)(al[tr] + (size_t)s * 512);
    }
#pragma unroll
    for (int nt = 0; nt < 2; ++nt) {
      Bh[nt] = *(const bf16x8*)(bh[nt] + (size_t)s * 512);
      Bl[nt] = *(const bf16x8*)(bl[nt] + (size_t)s * 512);
    }
#pragma unroll
    for (int nt = 0; nt < 2; ++nt) {
#pragma unroll
      for (int tr = 0; tr < 2; ++tr) {
        acc[tr][nt] = __builtin_amdgcn_mfma_f32_16x16x32_bf16(Ah[tr], Bh[nt], acc[tr][nt], 0, 0, 0);
        acc[tr][nt] = __builtin_amdgcn_mfma_f32_16x16x32_bf16(Ah[tr], Bl[nt], acc[tr][nt], 0, 0, 0);
        acc[tr][nt] = __builtin_amdgcn_mfma_f32_16x16x32_bf16(Al[tr], Bh[nt], acc[tr][nt], 0, 0, 0);
      }
    }
  }

  const int r4 = 4 * (l >> 4), cc = (l & 15);
#pragma unroll
  for (int tr = 0; tr < 2; ++tr) {
#pragma unroll
    for (int nt = 0; nt < 2; ++nt) {
      int col = outcol0 + (ntg0 + nt) * 16 + cc;
#pragma unroll
      for (int rr = 0; rr < 4; ++rr) {
        int row = rowbase + tr * 16 + r4 + rr;
        if (row < N) {
          float v = acc[tr][nt][rr];
          C[(size_t)row * ldc + col] = v;
          if (Hb && col < 128) Hb[(size_t)row * D + col] = f2bf(v);
        }
      }
    }
  }
}

// ---------------- k1: weights M, Wc + zero bucket counters ----------------
__global__ __launch_bounds__(256) void k1_pre1(
    const float* __restrict__ Wq, const float* __restrict__ Wk,
    const float* __restrict__ W0, const float* __restrict__ W1,
    const float* __restrict__ Wv,
    float* __restrict__ M, float* __restrict__ Wc,
    int* __restrict__ cnt, int twoN) {
  int gid = blockIdx.x * 256 + threadIdx.x;
  if (gid < twoN) cnt[gid] = 0;
  int bx = blockIdx.x;
  if (bx < 64) {
    int r = bx * 2 + (threadIdx.x >> 7);
    int c = threadIdx.x & 127;
    float acc = 0.f;
    for (int d = 0; d < D; ++d) acc += Wq[r * D + d] * Wk[c * D + d];
    M[r * D + c] = acc;
  } else {
    int idx = (bx - 64) * 256 + threadIdx.x;
    int r = idx >> 7, c = idx & 127;
    float v;
    if (r < 128) v = W0[r * D + c];
    else if (r < 256) v = W1[(r - 128) * D + c];
    else v = -Wv[(r - 256) * D + c];
    Wc[idx] = v;
  }
}

// ---------------- k2: dst-range-partitioned fill (blocks < nfb) + WM (blocks >= nfb) ----------------
// Block group (blockIdx&7) owns dst range [grp*rng, grp*rng+rng): slot/counter lines
// become XCD-exclusive -> stores coalesce in that XCD's L2, single writeback.
__global__ __launch_bounds__(256) void k2_fill_pre2(
    const int* __restrict__ src1, const int* __restrict__ dst1,
    int* __restrict__ cnt1, int* __restrict__ slot1, int E1,
    const int* __restrict__ src2, const int* __restrict__ dst2,
    int* __restrict__ cnt2, int* __restrict__ slot2, int E2, int nfb,
    const float* __restrict__ Wc, const float* __restrict__ M,
    float* __restrict__ WM, int N) {
  if (blockIdx.x < (unsigned)nfb) {
    const int grp = blockIdx.x & 7;
    const int bid = blockIdx.x >> 3;
    const int nbg = nfb >> 3;                 // blocks per group
    const int rng = (N + 7) >> 3;
    const int rlo = grp * rng;
    const int rhi = (rlo + rng < N) ? rlo + rng : N;
    const int tid = bid * 256 + threadIdx.x;
    const int stride = nbg * 256;
    for (int e = tid; e < E1; e += stride) {
      int d = dst1[e];
      if (d >= rlo && d < rhi) {
        int pos = atomicAdd(&cnt1[d], 1);
        if (pos < CAP) slot1[d * CAP + pos] = src1[e];
      }
    }
    for (int e = tid; e < E2; e += stride) {
      int d = dst2[e];
      if (d >= rlo && d < rhi) {
        int pos = atomicAdd(&cnt2[d], 1);
        if (pos < CAP) slot2[d * CAP + pos] = src2[e];
      }
    }
  } else {
    int idx = (blockIdx.x - nfb) * 256 + threadIdx.x;
    if (idx >= 384 * D) return;
    int r = idx >> 7, c = idx & 127;
    float acc = 0.f;
    for (int k = 0; k < D; ++k) acc += Wc[r * D + k] * M[k * D + c];
    WM[idx] = acc;
  }
}

// ---------------- k3: fragment conversion (x frags + Hb + B/M frags) ----------------
__global__ __launch_bounds__(256) void k3_pre3cvt(
    const float* __restrict__ x,
    unsigned short* __restrict__ Afh, unsigned short* __restrict__ Afl,
    unsigned short* __restrict__ Hb, int ncvt,
    const float* __restrict__ Wc, const float* __restrict__ WM,
    const float* __restrict__ M,
    unsigned short* __restrict__ Bfh, unsigned short* __restrict__ Bfl,
    unsigned short* __restrict__ Mfh, unsigned short* __restrict__ Mfl) {
  int gid = blockIdx.x * 256 + threadIdx.x;
  if (gid < ncvt) {
    int row = gid >> 6, f = (gid & 63) * 2;
    float2 v = *(const float2*)&x[row * D + f];
    frag_write(Afh, Afl, row >> 4, row & 15, f, v.x, v.y);
    unsigned int p = (unsigned int)f2bf(v.x) | ((unsigned int)f2bf(v.y) << 16);
    *(unsigned int*)&Hb[(size_t)row * D + f] = p;
    return;
  }
  int idx = gid - ncvt;
  if (idx < 16 * 12 * 512) {
    int e = idx & 7, l = (idx >> 3) & 63;
    int s = (idx >> 9) % 12, ntg = idx / (12 * 512);
    int n2 = ntg * 16 + (l & 15);
    int k = s * 32 + (l >> 4) * 8 + e;
    float v = (n2 < 128) ? Wc[k * D + n2] : WM[k * D + (n2 - 128)];
    unsigned short h = f2bf(v);
    Bfh[idx] = h;
    Bfl[idx] = f2bf(v - bf2f(h));
  } else {
    int i2 = idx - 16 * 12 * 512;
    if (i2 >= 8 * 4 * 512) return;
    int e = i2 & 7, l = (i2 >> 3) & 63;
    int s = (i2 >> 9) & 3, ntg = i2 / (4 * 512);
    int n2 = ntg * 16 + (l & 15);
    int k = s * 32 + (l >> 4) * 8 + e;
    float v = M[k * D + n2];
    unsigned short h = f2bf(v);
    Mfh[i2] = h;
    Mfl[i2] = f2bf(v - bf2f(h));
  }
}

// ---------------- gather/aggregate: CSR1/CSR2 loops INTERLEAVED (8 gathers in flight) ----------------
__global__ __launch_bounds__(256) void agg_k(
    const float* __restrict__ h, int ldh,
    const float* __restrict__ qt,                  // ld 256
    const unsigned short* __restrict__ Hb,         // N x 128 bf16 (gather source)
    const int* __restrict__ cnt1, const int* __restrict__ slot1,
    const int* __restrict__ cnt2, const int* __restrict__ slot2,
    unsigned short* __restrict__ Afh, unsigned short* __restrict__ Afl, int N) {
  int gw = (int)((blockIdx.x * blockDim.x + threadIdx.x) >> 6);
  if (gw >= N) return;
  const int i = __builtin_amdgcn_readfirstlane(gw);
  const int l = threadIdx.x & 63;
  const int m = l & 15, g = l >> 4;
  const int c0 = m * 8;

  float q[8];
  *(float4*)&q[0] = *(const float4*)&qt[(size_t)i * 256 + c0];
  *(float4*)&q[4] = *(const float4*)&qt[(size_t)i * 256 + c0 + 4];

  float a1[8] = {0.f, 0.f, 0.f, 0.f, 0.f, 0.f, 0.f, 0.f};
  float a2[8] = {0.f, 0.f, 0.f, 0.f, 0.f, 0.f, 0.f, 0.f};

  const int* sp1 = slot1 + (size_t)i * CAP;
  const int* sp2 = slot2 + (size_t)i * CAP;
  int end1 = cnt1[i]; if (end1 > CAP) end1 = CAP;
  int end2 = cnt2[i]; if (end2 > CAP) end2 = CAP;
  const int maxe = (end1 > end2) ? end1 : end2;

  int nj1[4], nj2[4]; bool nv1[4], nv2[4];
#pragma unroll
  for (int u = 0; u < 4; ++u) {
    int ee = 4 * u + g;
    nv1[u] = ee < end1; nj1[u] = nv1[u] ? sp1[ee] : 0;
    nv2[u] = ee < end2; nj2[u] = nv2[u] ? sp2[ee] : 0;
  }

  for (int e = 0; e < maxe; e += 16) {
    int j1[4], j2[4]; bool v1[4], v2[4];
#pragma unroll
    for (int u = 0; u < 4; ++u) {
      j1[u] = nj1[u]; v1[u] = nv1[u];
      j2[u] = nj2[u]; v2[u] = nv2[u];
    }
    // issue all 8 gathers back-to-back (fills the memory pipe)
    uint4 w1[4], w2[4];
#pragma unroll
    for (int u = 0; u < 4; ++u) w1[u] = *(const uint4*)&Hb[(size_t)j1[u] * D + c0];
#pragma unroll
    for (int u = 0; u < 4; ++u) w2[u] = *(const uint4*)&Hb[(size_t)j2[u] * D + c0];
    // prefetch next batch indices for both CSRs
    int en = e + 16;
    if (en < maxe) {
#pragma unroll
      for (int u = 0; u < 4; ++u) {
        int ee = en + 4 * u + g;
        nv1[u] = ee < end1; nj1[u] = nv1[u] ? sp1[ee] : 0;
        nv2[u] = ee < end2; nj2[u] = nv2[u] ? sp2[ee] : 0;
      }
    }
    // CSR1 accumulate
#pragma unroll
    for (int u = 0; u < 4; ++u) {
      if (!v1[u]) w1[u] = make_uint4(0u, 0u, 0u, 0u);
      a1[0] += bf_lo(w1[u].x); a1[1] += bf_hi(w1[u].x);
      a1[2] += bf_lo(w1[u].y); a1[3] += bf_hi(w1[u].y);
      a1[4] += bf_lo(w1[u].z); a1[5] += bf_hi(w1[u].z);
      a1[6] += bf_lo(w1[u].w); a1[7] += bf_hi(w1[u].w);
    }
    // CSR2 accumulate
    float fv[4][8]; float p[4];
#pragma unroll
    for (int u = 0; u < 4; ++u) {
      if (!v2[u]) w2[u] = make_uint4(0u, 0u, 0u, 0u);
      fv[u][0] = bf_lo(w2[u].x); fv[u][1] = bf_hi(w2[u].x);
      fv[u][2] = bf_lo(w2[u].y); fv[u][3] = bf_hi(w2[u].y);
      fv[u][4] = bf_lo(w2[u].z); fv[u][5] = bf_hi(w2[u].z);
      fv[u][6] = bf_lo(w2[u].w); fv[u][7] = bf_hi(w2[u].w);
      p[u] = q[0] * fv[u][0] + q[1] * fv[u][1] + q[2] * fv[u][2] + q[3] * fv[u][3] +
             q[4] * fv[u][4] + q[5] * fv[u][5] + q[6] * fv[u][6] + q[7] * fv[u][7];
    }
#pragma unroll
    for (int ofs = 1; ofs < 16; ofs <<= 1) {
#pragma unroll
      for (int u = 0; u < 4; ++u) p[u] += __shfl_xor(p[u], ofs);
    }
#pragma unroll
    for (int u = 0; u < 4; ++u)
#pragma unroll
      for (int t = 0; t < 8; ++t) a2[t] += p[u] * fv[u][t];
  }

  // ---- cross-group combine ----
#pragma unroll
  for (int t = 0; t < 8; ++t) {
    a1[t] += __shfl_xor(a1[t], 16); a1[t] += __shfl_xor(a1[t], 32);
    a2[t] += __shfl_xor(a2[t], 16); a2[t] += __shfl_xor(a2[t], 32);
  }

  // ---- fragment writes: g=0 -> h row, g=1 -> a1, g=2 -> a2 ----
  if (g < 3) {
    float vals[8];
    if (g == 0) {
      *(float4*)&vals[0] = *(const float4*)&h[(size_t)i * ldh + c0];
      *(float4*)&vals[4] = *(const float4*)&h[(size_t)i * ldh + c0 + 4];
    } else if (g == 1) {
#pragma unroll
      for (int t = 0; t < 8; ++t) vals[t] = a1[t];
    } else {
#pragma unroll
      for (int t = 0; t < 8; ++t) vals[t] = a2[t];
    }
    uint4 hiw, low;
    split2(vals[0], vals[1], hiw.x, low.x);
    split2(vals[2], vals[3], hiw.y, low.y);
    split2(vals[4], vals[5], hiw.z, low.z);
    split2(vals[6], vals[7], hiw.w, low.w);
    size_t base = (((size_t)(i >> 4) * 12 + g * 4 + (m >> 2)) * 64 +
                   (i & 15) + 16 * (m & 3)) * 8;
    *(uint4*)&Afh[base] = hiw;
    *(uint4*)&Afl[base] = low;
  }
}

// ---------------- standalone GEMM (flat grid + bijective XCD swizzle) ----------------
__global__ __launch_bounds__(256) void gemm_mfma(
    const unsigned short* __restrict__ Afh, const unsigned short* __restrict__ Afl,
    int ksteps,
    const unsigned short* __restrict__ Bfh, const unsigned short* __restrict__ Bfl,
    int outcol0, float* __restrict__ C, int ldc,
    unsigned short* __restrict__ Hb, int N, int ntiles, int log2ny) {
  const int nwg = gridDim.x;
  const int flat = blockIdx.x;
  const int xcd = flat & 7;
  const int qq = nwg >> 3, rr8 = nwg & 7;
  const int wgid = (xcd < rr8 ? xcd * (qq + 1) : rr8 * (qq + 1) + (xcd - rr8) * qq) + (flat >> 3);
  gemm_tile(Afh, Afl, ksteps, Bfh, Bfl, outcol0, C, ldc, Hb, N, ntiles, log2ny, wgid);
}

// ---------------- host ----------------

extern "C" void kernel_launch(void* const* d_in, const int* in_sizes, int n_in,
                              void* d_out, int out_size, void* d_ws, size_t ws_size,
                              hipStream_t stream) {
  const float* x  = (const float*)d_in[0];
  const int* ei1  = (const int*)d_in[1];
  const int* ei2  = (const int*)d_in[2];
  const float* W0 = (const float*)d_in[3];
  const float* W1 = (const float*)d_in[4];
  const float* Wq = (const float*)d_in[5];
  const float* Wk = (const float*)d_in[6];
  const float* Wv = (const float*)d_in[7];

  const int N  = in_sizes[0] / D;
  const int E1 = in_sizes[1] / 2;
  const int E2 = in_sizes[2] / 2;
  const int* src1 = ei1;
  const int* dst1 = ei1 + E1;
  const int* src2 = ei2;
  const int* dst2 = ei2 + E2;
  const int TILES = (N + 15) / 16;

  float* Cbuf = (float*)d_ws;                       // N x 256
  float* M    = Cbuf + (size_t)N * 256;             // 128x128
  float* Wc   = M + 16384;                          // 384x128
  float* WM   = Wc + 49152;                         // 384x128
  unsigned short* Afh = (unsigned short*)(WM + 49152);   // TILES*12*512
  unsigned short* Afl = Afh + (size_t)TILES * 6144;
  unsigned short* Bfh = Afl + (size_t)TILES * 6144;      // 16*12*512
  unsigned short* Bfl = Bfh + 98304;
  unsigned short* Mfh = Bfl + 98304;                     // 8*4*512
  unsigned short* Mfl = Mfh + 16384;
  unsigned short* Hb  = Mfl + 16384;                     // N x 128 bf16
  int* cnt1  = (int*)(Hb + (size_t)N * D);          // N
  int* cnt2  = cnt1 + N;                            // N
  int* slot1 = cnt2 + N;                            // N*CAP
  int* slot2 = slot1 + (size_t)N * CAP;             // N*CAP

  size_t needed = ((size_t)N * 256 + 16384 + 2 * 49152) * 4ull +
                  ((size_t)2 * TILES * 6144 + 2 * 98304 + 2 * 16384 + (size_t)N * D) * 2ull +
                  ((size_t)2 * N + 2ull * N * CAP) * 4ull;
  if (ws_size < needed) return;

  float* out = (float*)d_out;

  const int gx = (N + 63) / 64;
  const int ablocks = (N * 64 + 255) / 256;
  const int ncvt = N * 64;
  const int tot3 = ncvt + 16 * 12 * 512 + 8 * 4 * 512;
  const int nfb = 1024;    // fill blocks: 128 per dst-range group

  // preamble: 4 dispatches; CSR = single dst-partitioned bucket-fill pass
  k1_pre1<<<256, 256, 0, stream>>>(Wq, Wk, W0, W1, Wv, M, Wc, cnt1, 2 * N);
  k2_fill_pre2<<<nfb + 192, 256, 0, stream>>>(src1, dst1, cnt1, slot1, E1,
                                              src2, dst2, cnt2, slot2, E2, nfb,
                                              Wc, M, WM, N);
  k3_pre3cvt<<<(tot3 + 255) / 256, 256, 0, stream>>>(x, Afh, Afl, Hb, ncvt,
                                                     Wc, WM, M, Bfh, Bfl, Mfh, Mfl);
  gemm_mfma<<<gx * 2, 256, 0, stream>>>(Afh, Afl, 4, Mfh, Mfl,
                                        128, Cbuf, 256, nullptr, N, TILES, 1);

  for (int s = 0; s < 5; ++s) {
    const float* hsrc = (s == 0) ? x : Cbuf;
    const int ldh = (s == 0) ? D : 256;

    agg_k<<<ablocks, 256, 0, stream>>>(hsrc, ldh, Cbuf + 128, Hb,
                                       cnt1, slot1, cnt2, slot2, Afh, Afl, N);

    if (s == 4) {
      gemm_mfma<<<gx * 2, 256, 0, stream>>>(Afh, Afl, 12, Bfh, Bfl,
                                            0, out, D, nullptr, N, TILES, 1);
    } else {
      gemm_mfma<<<gx * 4, 256, 0, stream>>>(Afh, Afl, 12, Bfh, Bfl,
                                            0, Cbuf, 256, Hb, N, TILES, 2);
    }
  }
}

// Round 18
// 259.191 us; speedup vs baseline: 1.0403x; 1.0403x over previous
//
#include <hip/hip_runtime.h>

#define D 128
#define CAP 96   // slot capacity per node; deg ~ Poisson(32), P(>96) ~ 1e-18

typedef __attribute__((ext_vector_type(8))) short bf16x8;
typedef __attribute__((ext_vector_type(4))) float f32x4;

// ---------------- bf16 helpers (RTN-even) ----------------
__device__ __forceinline__ unsigned short f2bf(float f) {
  union { float f; unsigned int u; } c; c.f = f;
  unsigned int u = c.u;
  unsigned int r = (u + 0x7fffu + ((u >> 16) & 1u)) >> 16;
  return (unsigned short)r;
}
__device__ __forceinline__ float bf2f(unsigned short h) {
  return __uint_as_float(((unsigned int)h) << 16);
}
__device__ __forceinline__ float bf_lo(unsigned int w) {
  return __uint_as_float(w << 16);
}
__device__ __forceinline__ float bf_hi(unsigned int w) {
  return __uint_as_float(w & 0xffff0000u);
}
__device__ __forceinline__ void split2(float a, float b, unsigned int& hi, unsigned int& lo) {
  unsigned short ha = f2bf(a), hb = f2bf(b);
  unsigned short la = f2bf(a - bf2f(ha)), lb = f2bf(b - bf2f(hb));
  hi = (unsigned int)ha | ((unsigned int)hb << 16);
  lo = (unsigned int)la | ((unsigned int)lb << 16);
}

// A-fragment layout: Af[((t*12 + s)*64 + (row&15) + 16*((k&31)>>3))*8 + (k&7)]
__device__ __forceinline__ void frag_write(unsigned short* __restrict__ Afh,
                                           unsigned short* __restrict__ Afl,
                                           int t, int r, int k, float a, float b) {
  unsigned int hh, hl;
  split2(a, b, hh, hl);
  int s = k >> 5, ksub = (k & 31) >> 3, e = k & 7;
  size_t addr = ((size_t)(t * 12 + s) * 64 + r + 16 * ksub) * 8 + e;
  *(unsigned int*)&Afh[addr] = hh;
  *(unsigned int*)&Afl[addr] = hl;
}

// ---------------- fill chunk: one 256-edge block of the bucket fill ----------------
__device__ void fill_chunk(int gfb,
                           const int* __restrict__ src1, const int* __restrict__ dst1,
                           int* __restrict__ cnt1, int* __restrict__ slot1, int E1,
                           const int* __restrict__ src2, const int* __restrict__ dst2,
                           int* __restrict__ cnt2, int* __restrict__ slot2, int E2) {
  int e = gfb * 256 + threadIdx.x;
  if (e < E1) {
    int d = dst1[e];
    int pos = atomicAdd(&cnt1[d], 1);
    if (pos < CAP) slot1[d * CAP + pos] = src1[e];
  }
  int e2 = e - E1;
  if (e2 >= 0 && e2 < E2) {
    int d = dst2[e2];
    int pos = atomicAdd(&cnt2[d], 1);
    if (pos < CAP) slot2[d * CAP + pos] = src2[e2];
  }
}

// ---------------- GEMM tile worker ----------------
__device__ void gemm_tile(
    const unsigned short* __restrict__ Afh, const unsigned short* __restrict__ Afl,
    int ksteps,
    const unsigned short* __restrict__ Bfh, const unsigned short* __restrict__ Bfl,
    int outcol0, float* __restrict__ C, int ldc,
    unsigned short* __restrict__ Hb, int N, int ntiles, int log2ny, int wgid) {
  const int w = threadIdx.x >> 6, l = threadIdx.x & 63;
  const int wr = w & 1, wc = w >> 1;
  const int rowblk = wgid >> log2ny;
  const int panel = wgid - (rowblk << log2ny);
  const int rowbase = rowblk * 64 + wr * 32;
  const int ntg0 = panel * 4 + wc * 2;

  int t_[2];
#pragma unroll
  for (int tr = 0; tr < 2; ++tr) {
    int t = (rowbase >> 4) + tr;
    t_[tr] = (t < ntiles) ? t : (ntiles - 1);
  }

  const size_t loff = (size_t)l * 8;
  const unsigned short* ah[2];
  const unsigned short* al[2];
#pragma unroll
  for (int tr = 0; tr < 2; ++tr) {
    ah[tr] = Afh + (size_t)t_[tr] * 12 * 512 + loff;
    al[tr] = Afl + (size_t)t_[tr] * 12 * 512 + loff;
  }
  const unsigned short* bh[2];
  const unsigned short* bl[2];
#pragma unroll
  for (int nt = 0; nt < 2; ++nt) {
    bh[nt] = Bfh + (size_t)(ntg0 + nt) * ksteps * 512 + loff;
    bl[nt] = Bfl + (size_t)(ntg0 + nt) * ksteps * 512 + loff;
  }

  f32x4 acc[2][2] = {};
  for (int s = 0; s < ksteps; ++s) {
    bf16x8 Ah[2], Al[2], Bh[2], Bl[2];
#pragma unroll
    for (int tr = 0; tr < 2; ++tr) {
      Ah[tr] = *(const bf16x8*)(ah[tr] + (size_t)s * 512);
      Al[tr] = *(const bf16x8*)(al[tr] + (size_t)s * 512);
    }
#pragma unroll
    for (int nt = 0; nt < 2; ++nt) {
      Bh[nt] = *(const bf16x8*)(bh[nt] + (size_t)s * 512);
      Bl[nt] = *(const bf16x8*)(bl[nt] + (size_t)s * 512);
    }
#pragma unroll
    for (int nt = 0; nt < 2; ++nt) {
#pragma unroll
      for (int tr = 0; tr < 2; ++tr) {
        acc[tr][nt] = __builtin_amdgcn_mfma_f32_16x16x32_bf16(Ah[tr], Bh[nt], acc[tr][nt], 0, 0, 0);
        acc[tr][nt] = __builtin_amdgcn_mfma_f32_16x16x32_bf16(Ah[tr], Bl[nt], acc[tr][nt], 0, 0, 0);
        acc[tr][nt] = __builtin_amdgcn_mfma_f32_16x16x32_bf16(Al[tr], Bh[nt], acc[tr][nt], 0, 0, 0);
      }
    }
  }

  const int r4 = 4 * (l >> 4), cc = (l & 15);
#pragma unroll
  for (int tr = 0; tr < 2; ++tr) {
#pragma unroll
    for (int nt = 0; nt < 2; ++nt) {
      int col = outcol0 + (ntg0 + nt) * 16 + cc;
#pragma unroll
      for (int rr = 0; rr < 4; ++rr) {
        int row = rowbase + tr * 16 + r4 + rr;
        if (row < N) {
          float v = acc[tr][nt][rr];
          C[(size_t)row * ldc + col] = v;
          if (Hb && col < 128) Hb[(size_t)row * D + col] = f2bf(v);
        }
      }
    }
  }
}

// ---------------- k1: weights M, Wc + zero bucket counters ----------------
__global__ __launch_bounds__(256) void k1_pre1(
    const float* __restrict__ Wq, const float* __restrict__ Wk,
    const float* __restrict__ W0, const float* __restrict__ W1,
    const float* __restrict__ Wv,
    float* __restrict__ M, float* __restrict__ Wc,
    int* __restrict__ cnt, int twoN) {
  int gid = blockIdx.x * 256 + threadIdx.x;
  if (gid < twoN) cnt[gid] = 0;
  int bx = blockIdx.x;
  if (bx < 64) {
    int r = bx * 2 + (threadIdx.x >> 7);
    int c = threadIdx.x & 127;
    float acc = 0.f;
    for (int d = 0; d < D; ++d) acc += Wq[r * D + d] * Wk[c * D + d];
    M[r * D + c] = acc;
  } else {
    int idx = (bx - 64) * 256 + threadIdx.x;
    int r = idx >> 7, c = idx & 127;
    float v;
    if (r < 128) v = W0[r * D + c];
    else if (r < 256) v = W1[(r - 128) * D + c];
    else v = -Wv[(r - 256) * D + c];
    Wc[idx] = v;
  }
}

// ---------------- k2: fill chunk (blocks < fb2) + WM=Wc@M (blocks >= fb2) ----------------
__global__ __launch_bounds__(256) void k2_fill_pre2(
    const int* __restrict__ src1, const int* __restrict__ dst1,
    int* __restrict__ cnt1, int* __restrict__ slot1, int E1,
    const int* __restrict__ src2, const int* __restrict__ dst2,
    int* __restrict__ cnt2, int* __restrict__ slot2, int E2, int fb2,
    const float* __restrict__ Wc, const float* __restrict__ M,
    float* __restrict__ WM) {
  if (blockIdx.x < (unsigned)fb2) {
    fill_chunk(blockIdx.x, src1, dst1, cnt1, slot1, E1,
               src2, dst2, cnt2, slot2, E2);
  } else {
    int idx = (blockIdx.x - fb2) * 256 + threadIdx.x;
    if (idx >= 384 * D) return;
    int r = idx >> 7, c = idx & 127;
    float acc = 0.f;
    for (int k = 0; k < D; ++k) acc += Wc[r * D + k] * M[k * D + c];
    WM[idx] = acc;
  }
}

// ---------------- k3: fill chunk (blocks < fb3) + frag conversion ----------------
__global__ __launch_bounds__(256) void k3_fill_pre3cvt(
    const int* __restrict__ src1, const int* __restrict__ dst1,
    int* __restrict__ cnt1, int* __restrict__ slot1, int E1,
    const int* __restrict__ src2, const int* __restrict__ dst2,
    int* __restrict__ cnt2, int* __restrict__ slot2, int E2,
    int fb3, int gfb0,
    const float* __restrict__ x,
    unsigned short* __restrict__ Afh, unsigned short* __restrict__ Afl,
    unsigned short* __restrict__ Hb, int ncvt,
    const float* __restrict__ Wc, const float* __restrict__ WM,
    const float* __restrict__ M,
    unsigned short* __restrict__ Bfh, unsigned short* __restrict__ Bfl,
    unsigned short* __restrict__ Mfh, unsigned short* __restrict__ Mfl) {
  if (blockIdx.x < (unsigned)fb3) {
    fill_chunk(gfb0 + blockIdx.x, src1, dst1, cnt1, slot1, E1,
               src2, dst2, cnt2, slot2, E2);
    return;
  }
  int gid = (blockIdx.x - fb3) * 256 + threadIdx.x;
  if (gid < ncvt) {
    int row = gid >> 6, f = (gid & 63) * 2;
    float2 v = *(const float2*)&x[row * D + f];
    frag_write(Afh, Afl, row >> 4, row & 15, f, v.x, v.y);
    unsigned int p = (unsigned int)f2bf(v.x) | ((unsigned int)f2bf(v.y) << 16);
    *(unsigned int*)&Hb[(size_t)row * D + f] = p;
    return;
  }
  int idx = gid - ncvt;
  if (idx < 16 * 12 * 512) {
    int e = idx & 7, l = (idx >> 3) & 63;
    int s = (idx >> 9) % 12, ntg = idx / (12 * 512);
    int n2 = ntg * 16 + (l & 15);
    int k = s * 32 + (l >> 4) * 8 + e;
    float v = (n2 < 128) ? Wc[k * D + n2] : WM[k * D + (n2 - 128)];
    unsigned short h = f2bf(v);
    Bfh[idx] = h;
    Bfl[idx] = f2bf(v - bf2f(h));
  } else {
    int i2 = idx - 16 * 12 * 512;
    if (i2 >= 8 * 4 * 512) return;
    int e = i2 & 7, l = (i2 >> 3) & 63;
    int s = (i2 >> 9) & 3, ntg = i2 / (4 * 512);
    int n2 = ntg * 16 + (l & 15);
    int k = s * 32 + (l >> 4) * 8 + e;
    float v = M[k * D + n2];
    unsigned short h = f2bf(v);
    Mfh[i2] = h;
    Mfl[i2] = f2bf(v - bf2f(h));
  }
}

// ---------------- k4: fill chunk (blocks < fb4) + Qt gemm ----------------
__global__ __launch_bounds__(256) void k4_fill_qtgemm(
    const int* __restrict__ src1, const int* __restrict__ dst1,
    int* __restrict__ cnt1, int* __restrict__ slot1, int E1,
    const int* __restrict__ src2, const int* __restrict__ dst2,
    int* __restrict__ cnt2, int* __restrict__ slot2, int E2,
    int fb4, int gfb0,
    const unsigned short* __restrict__ Afh, const unsigned short* __restrict__ Afl,
    const unsigned short* __restrict__ Mfh, const unsigned short* __restrict__ Mfl,
    float* __restrict__ Cbuf, int N, int ntiles) {
  if (blockIdx.x < (unsigned)fb4) {
    fill_chunk(gfb0 + blockIdx.x, src1, dst1, cnt1, slot1, E1,
               src2, dst2, cnt2, slot2, E2);
  } else {
    gemm_tile(Afh, Afl, 4, Mfh, Mfl, 128, Cbuf, 256, nullptr, N, ntiles, 1,
              blockIdx.x - fb4);
  }
}

// ---------------- gather/aggregate (R16 form): 1 wave/node, 4x16 lanes, MLP=4 ----------------
__global__ __launch_bounds__(256) void agg_k(
    const float* __restrict__ h, int ldh,
    const float* __restrict__ qt,                  // ld 256
    const unsigned short* __restrict__ Hb,         // N x 128 bf16 (gather source)
    const int* __restrict__ cnt1, const int* __restrict__ slot1,
    const int* __restrict__ cnt2, const int* __restrict__ slot2,
    unsigned short* __restrict__ Afh, unsigned short* __restrict__ Afl, int N) {
  int gw = (int)((blockIdx.x * blockDim.x + threadIdx.x) >> 6);
  if (gw >= N) return;
  const int i = __builtin_amdgcn_readfirstlane(gw);
  const int l = threadIdx.x & 63;
  const int m = l & 15, g = l >> 4;
  const int c0 = m * 8;

  float q[8];
  *(float4*)&q[0] = *(const float4*)&qt[(size_t)i * 256 + c0];
  *(float4*)&q[4] = *(const float4*)&qt[(size_t)i * 256 + c0 + 4];

  float a1[8] = {0.f, 0.f, 0.f, 0.f, 0.f, 0.f, 0.f, 0.f};
  float a2[8] = {0.f, 0.f, 0.f, 0.f, 0.f, 0.f, 0.f, 0.f};

  // ---- CSR1: neighbor sum ----
  {
    const int* sp = slot1 + (size_t)i * CAP;
    int end = cnt1[i]; if (end > CAP) end = CAP;
    int nj[4]; bool nv[4];
#pragma unroll
    for (int u = 0; u < 4; ++u) {
      int ee = 4 * u + g;
      nv[u] = ee < end; nj[u] = nv[u] ? sp[ee] : 0;
    }
    for (int e = 0; e < end; e += 16) {
      int j[4]; bool v[4];
#pragma unroll
      for (int u = 0; u < 4; ++u) { j[u] = nj[u]; v[u] = nv[u]; }
      int en = e + 16;
      if (en < end) {
#pragma unroll
        for (int u = 0; u < 4; ++u) {
          int ee = en + 4 * u + g;
          nv[u] = ee < end; nj[u] = nv[u] ? sp[ee] : 0;
        }
      }
      uint4 w[4];
#pragma unroll
      for (int u = 0; u < 4; ++u)
        w[u] = *(const uint4*)&Hb[(size_t)j[u] * D + c0];
#pragma unroll
      for (int u = 0; u < 4; ++u) {
        if (!v[u]) w[u] = make_uint4(0u, 0u, 0u, 0u);
        a1[0] += bf_lo(w[u].x); a1[1] += bf_hi(w[u].x);
        a1[2] += bf_lo(w[u].y); a1[3] += bf_hi(w[u].y);
        a1[4] += bf_lo(w[u].z); a1[5] += bf_hi(w[u].z);
        a1[6] += bf_lo(w[u].w); a1[7] += bf_hi(w[u].w);
      }
    }
  }

  // ---- CSR2: attention aggregate ----
  {
    const int* sp = slot2 + (size_t)i * CAP;
    int end = cnt2[i]; if (end > CAP) end = CAP;
    int nj[4]; bool nv[4];
#pragma unroll
    for (int u = 0; u < 4; ++u) {
      int ee = 4 * u + g;
      nv[u] = ee < end; nj[u] = nv[u] ? sp[ee] : 0;
    }
    for (int e = 0; e < end; e += 16) {
      int j[4]; bool v[4];
#pragma unroll
      for (int u = 0; u < 4; ++u) { j[u] = nj[u]; v[u] = nv[u]; }
      int en = e + 16;
      if (en < end) {
#pragma unroll
        for (int u = 0; u < 4; ++u) {
          int ee = en + 4 * u + g;
          nv[u] = ee < end; nj[u] = nv[u] ? sp[ee] : 0;
        }
      }
      uint4 w[4];
#pragma unroll
      for (int u = 0; u < 4; ++u)
        w[u] = *(const uint4*)&Hb[(size_t)j[u] * D + c0];
      float fv[4][8]; float p[4];
#pragma unroll
      for (int u = 0; u < 4; ++u) {
        if (!v[u]) w[u] = make_uint4(0u, 0u, 0u, 0u);
        fv[u][0] = bf_lo(w[u].x); fv[u][1] = bf_hi(w[u].x);
        fv[u][2] = bf_lo(w[u].y); fv[u][3] = bf_hi(w[u].y);
        fv[u][4] = bf_lo(w[u].z); fv[u][5] = bf_hi(w[u].z);
        fv[u][6] = bf_lo(w[u].w); fv[u][7] = bf_hi(w[u].w);
        p[u] = q[0] * fv[u][0] + q[1] * fv[u][1] + q[2] * fv[u][2] + q[3] * fv[u][3] +
               q[4] * fv[u][4] + q[5] * fv[u][5] + q[6] * fv[u][6] + q[7] * fv[u][7];
      }
#pragma unroll
      for (int ofs = 1; ofs < 16; ofs <<= 1) {
#pragma unroll
        for (int u = 0; u < 4; ++u) p[u] += __shfl_xor(p[u], ofs);
      }
#pragma unroll
      for (int u = 0; u < 4; ++u)
#pragma unroll
        for (int t = 0; t < 8; ++t) a2[t] += p[u] * fv[u][t];
    }
  }

  // ---- cross-group combine ----
#pragma unroll
  for (int t = 0; t < 8; ++t) {
    a1[t] += __shfl_xor(a1[t], 16); a1[t] += __shfl_xor(a1[t], 32);
    a2[t] += __shfl_xor(a2[t], 16); a2[t] += __shfl_xor(a2[t], 32);
  }

  // ---- fragment writes: g=0 -> h row, g=1 -> a1, g=2 -> a2 ----
  if (g < 3) {
    float vals[8];
    if (g == 0) {
      *(float4*)&vals[0] = *(const float4*)&h[(size_t)i * ldh + c0];
      *(float4*)&vals[4] = *(const float4*)&h[(size_t)i * ldh + c0 + 4];
    } else if (g == 1) {
#pragma unroll
      for (int t = 0; t < 8; ++t) vals[t] = a1[t];
    } else {
#pragma unroll
      for (int t = 0; t < 8; ++t) vals[t] = a2[t];
    }
    uint4 hiw, low;
    split2(vals[0], vals[1], hiw.x, low.x);
    split2(vals[2], vals[3], hiw.y, low.y);
    split2(vals[4], vals[5], hiw.z, low.z);
    split2(vals[6], vals[7], hiw.w, low.w);
    size_t base = (((size_t)(i >> 4) * 12 + g * 4 + (m >> 2)) * 64 +
                   (i & 15) + 16 * (m & 3)) * 8;
    *(uint4*)&Afh[base] = hiw;
    *(uint4*)&Afl[base] = low;
  }
}

// ---------------- standalone GEMM (flat grid + bijective XCD swizzle) ----------------
__global__ __launch_bounds__(256) void gemm_mfma(
    const unsigned short* __restrict__ Afh, const unsigned short* __restrict__ Afl,
    int ksteps,
    const unsigned short* __restrict__ Bfh, const unsigned short* __restrict__ Bfl,
    int outcol0, float* __restrict__ C, int ldc,
    unsigned short* __restrict__ Hb, int N, int ntiles, int log2ny) {
  const int nwg = gridDim.x;
  const int flat = blockIdx.x;
  const int xcd = flat & 7;
  const int qq = nwg >> 3, rr8 = nwg & 7;
  const int wgid = (xcd < rr8 ? xcd * (qq + 1) : rr8 * (qq + 1) + (xcd - rr8) * qq) + (flat >> 3);
  gemm_tile(Afh, Afl, ksteps, Bfh, Bfl, outcol0, C, ldc, Hb, N, ntiles, log2ny, wgid);
}

// ---------------- host ----------------

extern "C" void kernel_launch(void* const* d_in, const int* in_sizes, int n_in,
                              void* d_out, int out_size, void* d_ws, size_t ws_size,
                              hipStream_t stream) {
  const float* x  = (const float*)d_in[0];
  const int* ei1  = (const int*)d_in[1];
  const int* ei2  = (const int*)d_in[2];
  const float* W0 = (const float*)d_in[3];
  const float* W1 = (const float*)d_in[4];
  const float* Wq = (const float*)d_in[5];
  const float* Wk = (const float*)d_in[6];
  const float* Wv = (const float*)d_in[7];

  const int N  = in_sizes[0] / D;
  const int E1 = in_sizes[1] / 2;
  const int E2 = in_sizes[2] / 2;
  const int* src1 = ei1;
  const int* dst1 = ei1 + E1;
  const int* src2 = ei2;
  const int* dst2 = ei2 + E2;
  const int TILES = (N + 15) / 16;

  float* Cbuf = (float*)d_ws;                       // N x 256
  float* M    = Cbuf + (size_t)N * 256;             // 128x128
  float* Wc   = M + 16384;                          // 384x128
  float* WM   = Wc + 49152;                         // 384x128
  unsigned short* Afh = (unsigned short*)(WM + 49152);   // TILES*12*512
  unsigned short* Afl = Afh + (size_t)TILES * 6144;
  unsigned short* Bfh = Afl + (size_t)TILES * 6144;      // 16*12*512
  unsigned short* Bfl = Bfh + 98304;
  unsigned short* Mfh = Bfl + 98304;                     // 8*4*512
  unsigned short* Mfl = Mfh + 16384;
  unsigned short* Hb  = Mfl + 16384;                     // N x 128 bf16
  int* cnt1  = (int*)(Hb + (size_t)N * D);          // N
  int* cnt2  = cnt1 + N;                            // N
  int* slot1 = cnt2 + N;                            // N*CAP
  int* slot2 = slot1 + (size_t)N * CAP;             // N*CAP

  size_t needed = ((size_t)N * 256 + 16384 + 2 * 49152) * 4ull +
                  ((size_t)2 * TILES * 6144 + 2 * 98304 + 2 * 16384 + (size_t)N * D) * 2ull +
                  ((size_t)2 * N + 2ull * N * CAP) * 4ull;
  if (ws_size < needed) return;

  float* out = (float*)d_out;

  const int gx = (N + 63) / 64;
  const int ablocks = (N * 64 + 255) / 256;
  const int ncvt = N * 64;
  const int tot3 = ncvt + 16 * 12 * 512 + 8 * 4 * 512;
  const int k3b = (tot3 + 255) / 256;

  // fill distributed across k2/k3/k4 (45% / 35% / 20%)
  const int ebt = (E1 + E2 + 255) / 256;
  const int fb2 = (ebt * 45) / 100;
  const int fb3 = (ebt * 35) / 100;
  const int fb4 = ebt - fb2 - fb3;

  k1_pre1<<<256, 256, 0, stream>>>(Wq, Wk, W0, W1, Wv, M, Wc, cnt1, 2 * N);
  k2_fill_pre2<<<fb2 + 192, 256, 0, stream>>>(src1, dst1, cnt1, slot1, E1,
                                              src2, dst2, cnt2, slot2, E2, fb2,
                                              Wc, M, WM);
  k3_fill_pre3cvt<<<fb3 + k3b, 256, 0, stream>>>(
      src1, dst1, cnt1, slot1, E1, src2, dst2, cnt2, slot2, E2, fb3, fb2,
      x, Afh, Afl, Hb, ncvt, Wc, WM, M, Bfh, Bfl, Mfh, Mfl);
  k4_fill_qtgemm<<<fb4 + gx * 2, 256, 0, stream>>>(
      src1, dst1, cnt1, slot1, E1, src2, dst2, cnt2, slot2, E2, fb4, fb2 + fb3,
      Afh, Afl, Mfh, Mfl, Cbuf, N, TILES);

  for (int s = 0; s < 5; ++s) {
    const float* hsrc = (s == 0) ? x : Cbuf;
    const int ldh = (s == 0) ? D : 256;

    agg_k<<<ablocks, 256, 0, stream>>>(hsrc, ldh, Cbuf + 128, Hb,
                                       cnt1, slot1, cnt2, slot2, Afh, Afl, N);

    if (s == 4) {
      gemm_mfma<<<gx * 2, 256, 0, stream>>>(Afh, Afl, 12, Bfh, Bfl,
                                            0, out, D, nullptr, N, TILES, 1);
    } else {
      gemm_mfma<<<gx * 4, 256, 0, stream>>>(Afh, Afl, 12, Bfh, Bfl,
                                            0, Cbuf, 256, Hb, N, TILES, 2);
    }
  }
}